// Round 1
// baseline (685.433 us; speedup 1.0000x reference)
//
#include <hip/hip_runtime.h>
#include <math.h>

// Model: y[b,h,l] = (u *causal* f)[l] + u[b,h,l]*D_skip[h] + init[h,l]
// f[h,l]   = 2dt * sum_d q_d * Re(lambda_d^l),  lambda_d = exp((a_d + i*theta_d)*dt)
// init[h,l]= 2dt * sum_d w_d * Re(lambda_d^l),  q = b*c, w = 2*c*x0, a_d = -|a|
// Implemented as a chunked linear scan with state s_d = q_d*G_d + w_d*lambda^l:
//   s[l] = lambda*s[l-1] + q*u[l];  y[l] = 2dt*sum_d Re(s_d[l]) + u[l]*Dk

#define Bsz 16
#define Hn  256
#define Ln  4096
#define Dn  32
#define LC  64      // chunk length (per thread)
#define NCHUNK 64   // Ln / LC  == blockDim.x

__global__ __launch_bounds__(64, 2) void hyena_scan(
    const float* __restrict__ u,      // (B,H,L)
    const float* __restrict__ ain,    // (1,H,D)
    const float* __restrict__ thin,   // (1,H,D)
    const float* __restrict__ bin,    // (1,H,D)
    const float* __restrict__ cin,    // (1,H,D)
    const float* __restrict__ x0in,   // (1,H,D)
    const float* __restrict__ Dsk,    // (1,H)
    float* __restrict__ out)          // (B,H,L)
{
    __shared__ float S[NCHUNK][2 * Dn + 1];   // stride 65 -> conflict-free
    __shared__ float Ca[Dn], Cth[Dn], Clr[Dn], Cli[Dn], Cl64r[Dn], Cl64i[Dn], Cq[Dn], Cw[Dn];

    const int bh = blockIdx.x;        // b*H + h  (C==1 so output rows match)
    const int h  = bh & (Hn - 1);
    const int j  = threadIdx.x;       // chunk index 0..63
    const float dt = 1.0f / (float)(Ln - 1);

    // ---- per-(h,d) coefficients (lanes 0..31) ----
    if (j < Dn) {
        int idx = h * Dn + j;
        float av = -fabsf(ain[idx]);
        float th = thin[idx];
        float bv = bin[idx];
        float cv = cin[idx];
        float xv = x0in[idx];
        Ca[j]  = av;
        Cth[j] = th;
        Cq[j]  = bv * cv;
        Cw[j]  = 2.0f * cv * xv;
        float e1 = __expf(av * dt);
        float s1, c1; __sincosf(th * dt, &s1, &c1);
        Clr[j] = e1 * c1;  Cli[j] = e1 * s1;
        float e64 = __expf(av * dt * (float)LC);
        float s64, c64; __sincosf(th * dt * (float)LC, &s64, &c64);
        Cl64r[j] = e64 * c64;  Cl64i[j] = e64 * s64;
    }
    __syncthreads();

    float lr[Dn], li[Dn];
    #pragma unroll
    for (int d = 0; d < Dn; ++d) { lr[d] = Clr[d]; li[d] = Cli[d]; }

    const float*  urow = u + (size_t)bh * Ln + j * LC;
    const float4* u4   = (const float4*)urow;

    // ---- pass A: local G-scan from zero, keep chunk-final states ----
    float gr[Dn], gi[Dn];
    #pragma unroll
    for (int d = 0; d < Dn; ++d) { gr[d] = 0.0f; gi[d] = 0.0f; }

    #pragma unroll 1
    for (int k = 0; k < LC / 4; ++k) {
        float4 uv = u4[k];
        float uu[4] = {uv.x, uv.y, uv.z, uv.w};
        #pragma unroll
        for (int e = 0; e < 4; ++e) {
            float uval = uu[e];
            #pragma unroll
            for (int d = 0; d < Dn; ++d) {
                float t  = fmaf(-li[d], gi[d], uval);
                float nr = fmaf(lr[d], gr[d], t);
                gi[d] = fmaf(lr[d], gi[d], li[d] * gr[d]);
                gr[d] = nr;
            }
        }
    }

    #pragma unroll
    for (int d = 0; d < Dn; ++d) {
        S[j][2 * d]     = gr[d];
        S[j][2 * d + 1] = gi[d];
    }
    __syncthreads();

    // ---- combine: sequential carry scan across chunks (lane = d) ----
    if (j < Dn) {
        const int d = j;
        const float l64r = Cl64r[d], l64i = Cl64i[d];
        float cr = 0.0f, ci = 0.0f;          // carry_0 = G[-1] = 0
        for (int jj = 0; jj < NCHUNK; ++jj) {
            float fr = S[jj][2 * d], fi = S[jj][2 * d + 1];
            S[jj][2 * d]     = cr;           // carry_jj = G[jj*LC - 1]
            S[jj][2 * d + 1] = ci;
            float ncr = fmaf(l64r, cr, fmaf(-l64i, ci, fr));
            float nci = fmaf(l64r, ci, fmaf( l64i, cr, fi));
            cr = ncr; ci = nci;
        }
    }
    __syncthreads();

    // ---- pass B: s-form scan (carry + init folded into the initial state) ----
    float q[Dn], sr[Dn], si[Dn];
    const float t1 = dt * (float)(j * LC - 1);   // zk at l = j*LC - 1 (j=0 -> -dt, i.e. lambda^-1)
    #pragma unroll
    for (int d = 0; d < Dn; ++d) {
        float cr = S[j][2 * d], ci = S[j][2 * d + 1];
        q[d] = Cq[d];
        float wv  = Cw[d];
        float mag = __expf(Ca[d] * t1);
        float sn, cs; __sincosf(Cth[d] * t1, &sn, &cs);
        sr[d] = fmaf(q[d], cr, wv * mag * cs);   // s = q*G + w*lambda^l
        si[d] = fmaf(q[d], ci, wv * mag * sn);
    }

    const float Dk = Dsk[h];
    const float two_dt = 2.0f * dt;
    float4* o4 = (float4*)(out + (size_t)bh * Ln + j * LC);

    #pragma unroll 1
    for (int k = 0; k < LC / 4; ++k) {
        float4 uv = u4[k];
        float uu[4] = {uv.x, uv.y, uv.z, uv.w};
        float yv[4];
        #pragma unroll
        for (int e = 0; e < 4; ++e) {
            float uval = uu[e];
            float a0 = 0.0f, a1 = 0.0f, a2 = 0.0f, a3 = 0.0f;
            #pragma unroll
            for (int d = 0; d < Dn; ++d) {
                float m  = q[d] * uval;
                float t  = fmaf(-li[d], si[d], m);
                float nr = fmaf(lr[d], sr[d], t);
                si[d] = fmaf(lr[d], si[d], li[d] * sr[d]);
                sr[d] = nr;
                if ((d & 3) == 0)      a0 += nr;
                else if ((d & 3) == 1) a1 += nr;
                else if ((d & 3) == 2) a2 += nr;
                else                   a3 += nr;
            }
            float acc = (a0 + a1) + (a2 + a3);
            yv[e] = fmaf(uval, Dk, two_dt * acc);
        }
        float4 ov; ov.x = yv[0]; ov.y = yv[1]; ov.z = yv[2]; ov.w = yv[3];
        o4[k] = ov;
    }
}

extern "C" void kernel_launch(void* const* d_in, const int* in_sizes, int n_in,
                              void* d_out, int out_size, void* d_ws, size_t ws_size,
                              hipStream_t stream) {
    const float* u   = (const float*)d_in[0];
    const float* a   = (const float*)d_in[1];
    const float* th  = (const float*)d_in[2];
    const float* b   = (const float*)d_in[3];
    const float* c   = (const float*)d_in[4];
    const float* x0  = (const float*)d_in[5];
    const float* Dsk = (const float*)d_in[6];
    float* out = (float*)d_out;

    hipLaunchKernelGGL(hyena_scan, dim3(Bsz * Hn), dim3(NCHUNK), 0, stream,
                       u, a, th, b, c, x0, Dsk, out);
}

// Round 4
// 261.885 us; speedup vs baseline: 2.6173x; 2.6173x over previous
//
#include <hip/hip_runtime.h>
#include <math.h>

// y[b,h,l] = (u *causal* f)[l] + u[b,h,l]*D_skip[h] + init[h,l]
// f[h,l]   = 2dt * sum_d q_d * Re(lambda_d^l),  lambda_d = exp((a_d + i*theta_d)*dt)
// State-space scan: s = lambda*s + q*u;  y = 2dt*sum_d Re(s) + u*Dk
// (init term folded into s's initial value: s = q*G + w*lambda^l, w = 2*c*x0)
//
// Decomposition: block = 256 threads = one (b,h) row.
//   thread -> (chunk j = tid>>2 of 64 elements, d-group g = tid&3 of 8 states)
//   pass A: local G-scan; intra-wave Kogge-Stone shuffle scan over chunks;
//   1KB LDS for inter-wave carries; pass B: s-scan + 4-lane reduce + coalesced IO.

#define Hn  256
#define Ln  4096
#define Dn  32
#define DT  8       // d-states per thread
#define LC  64      // elements per chunk
#define TPB 256

__global__ __launch_bounds__(TPB, 4) void hyena_scan(
    const float* __restrict__ u,      // (B,H,L)
    const float* __restrict__ ain,    // (1,H,D)
    const float* __restrict__ thin,   // (1,H,D)
    const float* __restrict__ bin,    // (1,H,D)
    const float* __restrict__ cin,    // (1,H,D)
    const float* __restrict__ x0in,   // (1,H,D)
    const float* __restrict__ Dsk,    // (1,H)
    float* __restrict__ out)          // (B,H,L)
{
    __shared__ float WT[4][2 * Dn];   // per-wave chunk-scan totals (complex)

    const int bh   = blockIdx.x;
    const int h    = bh & (Hn - 1);
    const int tid  = threadIdx.x;
    const int g    = tid & 3;         // d-group
    const int j    = tid >> 2;        // global chunk 0..63
    const int m    = j & 15;          // chunk index within wave
    const int wid  = tid >> 6;        // wave 0..3
    const int lane = tid & 63;
    const int gb   = lane & ~3;       // group base lane
    const float dt = 1.0f / (float)(Ln - 1);

    // ---- per-(h,d) coefficients for this thread's 8 d's ----
    float av[DT], tv[DT], q[DT], w0[DT], lr[DT], li[DT];
    const int cbase = h * Dn + g * DT;
    #pragma unroll
    for (int dd = 0; dd < DT; ++dd) {
        av[dd] = -fabsf(ain[cbase + dd]);
        tv[dd] = thin[cbase + dd];
        float bv = bin[cbase + dd], cv = cin[cbase + dd], xv = x0in[cbase + dd];
        q[dd]  = bv * cv;
        w0[dd] = 2.0f * cv * xv;
        float e1 = __expf(av[dd] * dt);
        float s1, c1; __sincosf(tv[dd] * dt, &s1, &c1);
        lr[dd] = e1 * c1; li[dd] = e1 * s1;
    }

    const float4* u4g = (const float4*)(u + (size_t)bh * Ln) + j * 16;

    // ---- pass A: local G-scan from zero (group-coalesced loads + broadcast) ----
    float gr[DT], gi[DT];
    #pragma unroll
    for (int dd = 0; dd < DT; ++dd) { gr[dd] = 0.0f; gi[dd] = 0.0f; }

    #pragma unroll
    for (int kk = 0; kk < 4; ++kk) {
        float4 uf = u4g[kk * 4 + g];          // 4 lanes/group cover one 64B line
        #pragma unroll
        for (int sg = 0; sg < 4; ++sg) {
            int sl = gb + sg;
            float uu[4];
            uu[0] = __shfl(uf.x, sl, 64);
            uu[1] = __shfl(uf.y, sl, 64);
            uu[2] = __shfl(uf.z, sl, 64);
            uu[3] = __shfl(uf.w, sl, 64);
            #pragma unroll
            for (int c = 0; c < 4; ++c) {
                float uval = uu[c];
                #pragma unroll
                for (int dd = 0; dd < DT; ++dd) {
                    float t  = fmaf(-li[dd], gi[dd], uval);
                    float nr = fmaf(lr[dd], gr[dd], t);
                    gi[dd] = fmaf(lr[dd], gi[dd], li[dd] * gr[dd]);
                    gr[dd] = nr;
                }
            }
        }
    }

    // ---- intra-wave Kogge-Stone scan over the 16 chunks (stride-4 lanes) ----
    float pr[DT], pi[DT];                     // lambda^64, squared each step
    const float dt64 = dt * (float)LC;
    #pragma unroll
    for (int dd = 0; dd < DT; ++dd) {
        float e = __expf(av[dd] * dt64);
        float s, c; __sincosf(tv[dd] * dt64, &s, &c);
        pr[dd] = e * c; pi[dd] = e * s;
    }
    #pragma unroll
    for (int st = 1; st < 16; st <<= 1) {
        int src = lane - st * 4; if (src < 0) src = lane;
        #pragma unroll
        for (int dd = 0; dd < DT; ++dd) {
            float vr = __shfl(gr[dd], src, 64);
            float vi = __shfl(gi[dd], src, 64);
            vr = (m >= st) ? vr : 0.0f;
            vi = (m >= st) ? vi : 0.0f;
            gr[dd] = fmaf(pr[dd], vr, fmaf(-pi[dd], vi, gr[dd]));
            gi[dd] = fmaf(pr[dd], vi, fmaf( pi[dd], vr, gi[dd]));
        }
        #pragma unroll
        for (int dd = 0; dd < DT; ++dd) {     // p <- p^2
            float nr = fmaf(pr[dd], pr[dd], -(pi[dd] * pi[dd]));
            float ni = 2.0f * pr[dd] * pi[dd];
            pr[dd] = nr; pi[dd] = ni;
        }
    }
    // p now = lambda^1024 (wave-span multiplier)

    // ---- inter-wave carry via 1KB LDS ----
    if (m == 15) {
        #pragma unroll
        for (int dd = 0; dd < DT; ++dd) {
            WT[wid][2 * (g * DT + dd)]     = gr[dd];
            WT[wid][2 * (g * DT + dd) + 1] = gi[dd];
        }
    }
    __syncthreads();
    float cr[DT], ci[DT];
    #pragma unroll
    for (int dd = 0; dd < DT; ++dd) { cr[dd] = 0.0f; ci[dd] = 0.0f; }
    for (int v = 0; v < wid; ++v) {           // wave-uniform trip count
        #pragma unroll
        for (int dd = 0; dd < DT; ++dd) {
            float tr = WT[v][2 * (g * DT + dd)];
            float ti = WT[v][2 * (g * DT + dd) + 1];
            float nr = fmaf(pr[dd], cr[dd], fmaf(-pi[dd], ci[dd], tr));
            float ni = fmaf(pr[dd], ci[dd], fmaf( pi[dd], cr[dd], ti));
            cr[dd] = nr; ci[dd] = ni;
        }
    }

    // ---- entry carry + fold init: s = q*G_entry + w*lambda^(j*64-1) ----
    {
        int src4 = lane - 4; if (src4 < 0) src4 = lane;
        const float t1 = dt * (float)(j * LC - 1);
        #pragma unroll
        for (int dd = 0; dd < DT; ++dd) {
            float er = __shfl(gr[dd], src4, 64);   // exclusive intra-wave scan
            float ei = __shfl(gi[dd], src4, 64);
            er = (m >= 1) ? er : 0.0f;
            ei = (m >= 1) ? ei : 0.0f;
            float em = __expf(av[dd] * dt64 * (float)m);   // lambda^(64m)
            float sm, cm; __sincosf(tv[dd] * dt64 * (float)m, &sm, &cm);
            float amr = em * cm, ami = em * sm;
            float enr = er + fmaf(amr, cr[dd], -(ami * ci[dd]));
            float eni = ei + fmaf(amr, ci[dd],  (ami * cr[dd]));
            float mg = __expf(av[dd] * t1);
            float sn, cs; __sincosf(tv[dd] * t1, &sn, &cs);
            gr[dd] = fmaf(q[dd], enr, w0[dd] * mg * cs);   // reuse gr/gi as s
            gi[dd] = fmaf(q[dd], eni, w0[dd] * mg * sn);
        }
    }

    // ---- pass B: s-scan, 4-lane reduce, coalesced store ----
    const float Dk = Dsk[h];
    const float two_dt = 2.0f * dt;
    float4* o4g = (float4*)(out + (size_t)bh * Ln) + j * 16;

    #pragma unroll
    for (int kk = 0; kk < 4; ++kk) {
        float4 uf = u4g[kk * 4 + g];
        float ovv[4] = {0.0f, 0.0f, 0.0f, 0.0f};
        #pragma unroll
        for (int sg = 0; sg < 4; ++sg) {
            int sl = gb + sg;
            float uu[4];
            uu[0] = __shfl(uf.x, sl, 64);
            uu[1] = __shfl(uf.y, sl, 64);
            uu[2] = __shfl(uf.z, sl, 64);
            uu[3] = __shfl(uf.w, sl, 64);
            #pragma unroll
            for (int c = 0; c < 4; ++c) {
                float uval = uu[c];
                float a0 = 0.0f, a1 = 0.0f;
                #pragma unroll
                for (int dd = 0; dd < DT; ++dd) {
                    float mq = q[dd] * uval;
                    float t  = fmaf(-li[dd], gi[dd], mq);
                    float nr = fmaf(lr[dd], gr[dd], t);
                    gi[dd] = fmaf(lr[dd], gi[dd], li[dd] * gr[dd]);
                    gr[dd] = nr;
                    if (dd & 1) a1 += nr; else a0 += nr;
                }
                float ps = a0 + a1;
                ps += __shfl_xor(ps, 1, 64);
                ps += __shfl_xor(ps, 2, 64);
                float y = fmaf(uval, Dk, two_dt * ps);
                ovv[c] = (sg == g) ? y : ovv[c];
            }
        }
        float4 ov; ov.x = ovv[0]; ov.y = ovv[1]; ov.z = ovv[2]; ov.w = ovv[3];
        o4g[kk * 4 + g] = ov;
    }
}

extern "C" void kernel_launch(void* const* d_in, const int* in_sizes, int n_in,
                              void* d_out, int out_size, void* d_ws, size_t ws_size,
                              hipStream_t stream) {
    const float* u   = (const float*)d_in[0];
    const float* a   = (const float*)d_in[1];
    const float* th  = (const float*)d_in[2];
    const float* b   = (const float*)d_in[3];
    const float* c   = (const float*)d_in[4];
    const float* x0  = (const float*)d_in[5];
    const float* Dsk = (const float*)d_in[6];
    float* out = (float*)d_out;

    hipLaunchKernelGGL(hyena_scan, dim3(16 * Hn), dim3(TPB), 0, stream,
                       u, a, th, b, c, x0, Dsk, out);
}

// Round 5
// 252.164 us; speedup vs baseline: 2.7182x; 1.0385x over previous
//
#include <hip/hip_runtime.h>
#include <math.h>

// y[b,h,l] = (u *causal* f)[l] + u[b,h,l]*D_skip[h] + init[h,l]
// State-space scan: s = lambda*s + q*u;  y = 2dt*sum_d Re(s) + u*Dk
// lambda_d = exp((a_d + i*theta_d)*dt); init folded into s's initial value.
//
// block = 256 threads = one (b,h) row; thread = (chunk j = tid>>2, d-group g = tid&3, DT=8).
// Pass A: local G-scan (coalesced float4 + shfl broadcast), u stashed in LDS.
// Kogge-Stone shuffle scan over chunks + 1KB LDS inter-wave carry.
// Pass B: s-scan reading u from LDS, 4-lane reduce, coalesced store.
// All per-d transcendental-derived constants computed ONCE in the prologue so the
// raw (a,theta,w) arrays are dead in the main body -> peak ~110 VGPR, no spills.

#define Hn  256
#define Ln  4096
#define Dn  32
#define DT  8       // d-states per thread
#define LC  64      // elements per chunk
#define TPB 256
#define CSTRIDE 68  // LDS chunk stride in floats (4-word skew -> baseline banking)

__global__ __launch_bounds__(TPB, 4) void hyena_scan(
    const float* __restrict__ u,      // (B,H,L)
    const float* __restrict__ ain,    // (1,H,D)
    const float* __restrict__ thin,   // (1,H,D)
    const float* __restrict__ bin,    // (1,H,D)
    const float* __restrict__ cin,    // (1,H,D)
    const float* __restrict__ x0in,   // (1,H,D)
    const float* __restrict__ Dsk,    // (1,H)
    float* __restrict__ out)          // (B,H,L)
{
    __shared__ float uL[64 * CSTRIDE];   // 17408 B: u staged for pass B
    __shared__ float WT[4][2 * Dn];      // 1024 B: per-wave chunk-scan totals

    const int bh   = blockIdx.x;
    const int h    = bh & (Hn - 1);
    const int tid  = threadIdx.x;
    const int g    = tid & 3;            // d-group
    const int j    = tid >> 2;           // chunk 0..63
    const int m    = j & 15;             // chunk within wave
    const int wid  = tid >> 6;           // wave 0..3
    const int lane = tid & 63;
    const int gb   = lane & ~3;          // group base lane
    const float dt   = 1.0f / (float)(Ln - 1);
    const float dt64 = dt * (float)LC;

    // ---- prologue: ALL derived per-d constants; raw params die here ----
    float lr[DT], li[DT];                // lambda^1
    float pr[DT], pi[DT];                // lambda^64 (squared during scan -> lambda^1024)
    float amr[DT], ami[DT];              // lambda^(64m)
    float iwr[DT], iwi[DT];              // w * lambda^(j*64-1)  (init-state addend)
    float q[DT];
    {
        const int   cbase = h * Dn + g * DT;
        const float t1 = dt * (float)(j * LC - 1);
        const float tm = dt64 * (float)m;
        #pragma unroll
        for (int dd = 0; dd < DT; ++dd) {
            float av = -fabsf(ain[cbase + dd]);
            float tv = thin[cbase + dd];
            float bv = bin[cbase + dd], cv = cin[cbase + dd], xv = x0in[cbase + dd];
            q[dd] = bv * cv;
            float w = 2.0f * cv * xv;
            float e1 = __expf(av * dt);   float s1, c1; __sincosf(tv * dt,   &s1, &c1);
            lr[dd] = e1 * c1;  li[dd] = e1 * s1;
            float e2 = __expf(av * dt64); float s2, c2; __sincosf(tv * dt64, &s2, &c2);
            pr[dd] = e2 * c2;  pi[dd] = e2 * s2;
            float e3 = __expf(av * tm);   float s3, c3; __sincosf(tv * tm,   &s3, &c3);
            amr[dd] = e3 * c3; ami[dd] = e3 * s3;
            float e4 = __expf(av * t1);   float s4, c4; __sincosf(tv * t1,   &s4, &c4);
            iwr[dd] = w * e4 * c4; iwi[dd] = w * e4 * s4;
        }
    }

    const float4* u4g = (const float4*)(u + (size_t)bh * Ln) + j * 16;
    float* uLc = uL + j * CSTRIDE;

    // ---- pass A: local G-scan from zero; stash u in LDS ----
    float gr[DT], gi[DT];
    #pragma unroll
    for (int dd = 0; dd < DT; ++dd) { gr[dd] = 0.0f; gi[dd] = 0.0f; }

    #pragma unroll
    for (int kk = 0; kk < 4; ++kk) {
        float4 uf = u4g[kk * 4 + g];                    // 4 lanes/group = one 64B line
        *(float4*)(uLc + (kk * 4 + g) * 4) = uf;        // stage for pass B
        #pragma unroll
        for (int sg = 0; sg < 4; ++sg) {
            int sl = gb + sg;
            float uu[4];
            uu[0] = __shfl(uf.x, sl, 64);
            uu[1] = __shfl(uf.y, sl, 64);
            uu[2] = __shfl(uf.z, sl, 64);
            uu[3] = __shfl(uf.w, sl, 64);
            #pragma unroll
            for (int c = 0; c < 4; ++c) {
                float uval = uu[c];
                #pragma unroll
                for (int dd = 0; dd < DT; ++dd) {
                    float t  = fmaf(-li[dd], gi[dd], uval);
                    float nr = fmaf(lr[dd], gr[dd], t);
                    gi[dd] = fmaf(lr[dd], gi[dd], li[dd] * gr[dd]);
                    gr[dd] = nr;
                }
            }
        }
    }

    // ---- intra-wave Kogge-Stone scan over 16 chunks (stride-4 lanes) ----
    #pragma unroll
    for (int st = 1; st < 16; st <<= 1) {
        int src = lane - st * 4; if (src < 0) src = lane;
        #pragma unroll
        for (int dd = 0; dd < DT; ++dd) {
            float vr = __shfl(gr[dd], src, 64);
            float vi = __shfl(gi[dd], src, 64);
            vr = (m >= st) ? vr : 0.0f;
            vi = (m >= st) ? vi : 0.0f;
            gr[dd] = fmaf(pr[dd], vr, fmaf(-pi[dd], vi, gr[dd]));
            gi[dd] = fmaf(pr[dd], vi, fmaf( pi[dd], vr, gi[dd]));
        }
        #pragma unroll
        for (int dd = 0; dd < DT; ++dd) {               // p <- p^2
            float nr = fmaf(pr[dd], pr[dd], -(pi[dd] * pi[dd]));
            float ni = 2.0f * pr[dd] * pi[dd];
            pr[dd] = nr; pi[dd] = ni;
        }
    }
    // pr/pi now = lambda^1024 (wave-span multiplier)

    // ---- inter-wave carry via 1KB LDS ----
    if (m == 15) {
        #pragma unroll
        for (int dd = 0; dd < DT; ++dd) {
            WT[wid][2 * (g * DT + dd)]     = gr[dd];
            WT[wid][2 * (g * DT + dd) + 1] = gi[dd];
        }
    }
    __syncthreads();
    float cr[DT], ci[DT];
    #pragma unroll
    for (int dd = 0; dd < DT; ++dd) { cr[dd] = 0.0f; ci[dd] = 0.0f; }
    for (int v = 0; v < wid; ++v) {                     // wave-uniform trip count
        #pragma unroll
        for (int dd = 0; dd < DT; ++dd) {
            float tr = WT[v][2 * (g * DT + dd)];
            float ti = WT[v][2 * (g * DT + dd) + 1];
            float nr = fmaf(pr[dd], cr[dd], fmaf(-pi[dd], ci[dd], tr));
            float ni = fmaf(pr[dd], ci[dd], fmaf( pi[dd], cr[dd], ti));
            cr[dd] = nr; ci[dd] = ni;
        }
    }

    // ---- entry state: s = q*(excl_scan + lambda^(64m)*carry) + w*lambda^(j*64-1) ----
    {
        int src4 = lane - 4; if (src4 < 0) src4 = lane;
        #pragma unroll
        for (int dd = 0; dd < DT; ++dd) {
            float er = __shfl(gr[dd], src4, 64);        // exclusive intra-wave scan
            float ei = __shfl(gi[dd], src4, 64);
            er = (m >= 1) ? er : 0.0f;
            ei = (m >= 1) ? ei : 0.0f;
            float enr = er + fmaf(amr[dd], cr[dd], -(ami[dd] * ci[dd]));
            float eni = ei + fmaf(amr[dd], ci[dd],  (ami[dd] * cr[dd]));
            gr[dd] = fmaf(q[dd], enr, iwr[dd]);         // reuse gr/gi as s
            gi[dd] = fmaf(q[dd], eni, iwi[dd]);
        }
    }

    // ---- pass B: s-scan (u from LDS), 4-lane reduce, coalesced store ----
    const float Dk = Dsk[h];
    const float two_dt = 2.0f * dt;
    float4* o4g = (float4*)(out + (size_t)bh * Ln) + j * 16;

    #pragma unroll
    for (int kk = 0; kk < 4; ++kk) {
        float ovv[4] = {0.0f, 0.0f, 0.0f, 0.0f};
        #pragma unroll
        for (int sg = 0; sg < 4; ++sg) {
            float4 uf = *(const float4*)(uLc + (kk * 4 + sg) * 4);  // group broadcast
            float uu[4] = {uf.x, uf.y, uf.z, uf.w};
            #pragma unroll
            for (int c = 0; c < 4; ++c) {
                float uval = uu[c];
                float a0 = 0.0f, a1 = 0.0f;
                #pragma unroll
                for (int dd = 0; dd < DT; ++dd) {
                    float mq = q[dd] * uval;
                    float t  = fmaf(-li[dd], gi[dd], mq);
                    float nr = fmaf(lr[dd], gr[dd], t);
                    gi[dd] = fmaf(lr[dd], gi[dd], li[dd] * gr[dd]);
                    gr[dd] = nr;
                    if (dd & 1) a1 += nr; else a0 += nr;
                }
                float ps = a0 + a1;
                ps += __shfl_xor(ps, 1, 64);
                ps += __shfl_xor(ps, 2, 64);
                float y = fmaf(uval, Dk, two_dt * ps);
                ovv[c] = (sg == g) ? y : ovv[c];
            }
        }
        float4 ov; ov.x = ovv[0]; ov.y = ovv[1]; ov.z = ovv[2]; ov.w = ovv[3];
        o4g[kk * 4 + g] = ov;
    }
}

extern "C" void kernel_launch(void* const* d_in, const int* in_sizes, int n_in,
                              void* d_out, int out_size, void* d_ws, size_t ws_size,
                              hipStream_t stream) {
    const float* u   = (const float*)d_in[0];
    const float* a   = (const float*)d_in[1];
    const float* th  = (const float*)d_in[2];
    const float* b   = (const float*)d_in[3];
    const float* c   = (const float*)d_in[4];
    const float* x0  = (const float*)d_in[5];
    const float* Dsk = (const float*)d_in[6];
    float* out = (float*)d_out;

    hipLaunchKernelGGL(hyena_scan, dim3(16 * Hn), dim3(TPB), 0, stream,
                       u, a, th, b, c, x0, Dsk, out);
}

// Round 9
// 250.250 us; speedup vs baseline: 2.7390x; 1.0077x over previous
//
#include <hip/hip_runtime.h>
#include <math.h>

// y[b,h,l] = (u *causal* f)[l] + u[b,h,l]*D_skip[h] + init[h,l]
// State-space scan: s = lambda*s + q*u;  y = 2dt*sum_d Re(s) + u*Dk
// lambda_d = exp((a_d + i*theta_d)*dt); init folded into s's initial state.
//
// block = 256 threads = one (b,h) row; thread = (chunk j = tid>>2 of 64 elems,
// d-group g = tid&3 of DT=8 states). u staged once in LDS; both passes read it
// via broadcast ds_read_b128. Kogge-Stone shuffle scan over chunks + 1KB LDS
// inter-wave carry. Quad-perm DPP adds for the 4-lane reduce (no LDS pipe).
//
// VGPR-budget control (anti-spill), two independent mechanisms:
//  (a) amdgpu_waves_per_eu(4,4)
//  (b) LDS padded to 34.8KB/block -> max 4 blocks/CU, so the allocator's
//      occupancy target is 4 waves/SIMD -> 128-VGPR budget even if (a) ignored.

#define Hn  256
#define Ln  4096
#define Dn  32
#define DT  8       // d-states per thread
#define LC  64      // elements per chunk
#define TPB 256
#define CS  68      // LDS chunk stride in floats
#define LDSPAD 4096 // floats; forces 4 blocks/CU (see header comment)

__device__ __forceinline__ float dpp_add_x1(float v) {   // v += lane^1 (quad_perm)
    int t = __builtin_amdgcn_update_dpp(0, __float_as_int(v), 0xB1, 0xF, 0xF, true);
    return v + __int_as_float(t);
}
__device__ __forceinline__ float dpp_add_x2(float v) {   // v += lane^2 (quad_perm)
    int t = __builtin_amdgcn_update_dpp(0, __float_as_int(v), 0x4E, 0xF, 0xF, true);
    return v + __int_as_float(t);
}

__global__ __launch_bounds__(TPB)
__attribute__((amdgpu_waves_per_eu(4, 4)))
void hyena_scan(
    const float* __restrict__ u,      // (B,H,L)
    const float* __restrict__ ain,    // (1,H,D)
    const float* __restrict__ thin,   // (1,H,D)
    const float* __restrict__ bin,    // (1,H,D)
    const float* __restrict__ cin,    // (1,H,D)
    const float* __restrict__ x0in,   // (1,H,D)
    const float* __restrict__ Dsk,    // (1,H)
    float* __restrict__ out)          // (B,H,L)
{
    __shared__ float uL[64 * CS + LDSPAD];  // 17408B used + 16KB pad
    __shared__ float WT[4][2 * Dn];         // 1024 B: per-wave chunk-scan totals

    const int bh   = blockIdx.x;
    const int h    = bh & (Hn - 1);
    const int tid  = threadIdx.x;
    const int g    = tid & 3;         // d-group
    const int j    = tid >> 2;        // chunk 0..63
    const int m    = j & 15;          // chunk within wave
    const int wid  = tid >> 6;        // wave 0..3
    const int lane = tid & 63;
    const float dt   = 1.0f / (float)(Ln - 1);
    const float dt64 = dt * (float)LC;

    // ---- stage u into LDS (fully coalesced global reads) ----
    {
        const float4* ug = (const float4*)(u + (size_t)bh * Ln);
        #pragma unroll
        for (int r = 0; r < 4; ++r) {
            int i  = tid + r * TPB;          // float4 index 0..1023
            int cj = i >> 4, ct = i & 15;
            *(float4*)(uL + cj * CS + ct * 4) = ug[i];
        }
        // touch the pad so it cannot be discarded (one dword, no perf effect)
        if (tid == 0) uL[64 * CS + (bh & (LDSPAD - 1))] = 0.0f;
    }

    // ---- minimal live coefficient set ----
    float av[DT], tv[DT], q[DT], lr[DT], li[DT];
    {
        const int cbase = h * Dn + g * DT;
        #pragma unroll
        for (int dd = 0; dd < DT; ++dd) {
            av[dd] = -fabsf(ain[cbase + dd]);
            tv[dd] = thin[cbase + dd];
            q[dd]  = bin[cbase + dd] * cin[cbase + dd];
            float e1 = __expf(av[dd] * dt);
            float s1, c1; __sincosf(tv[dd] * dt, &s1, &c1);
            lr[dd] = e1 * c1; li[dd] = e1 * s1;
        }
    }
    __syncthreads();

    const float* uLc = uL + j * CS;

    // ---- pass A: local G-scan from zero (u via broadcast ds_read) ----
    float gr[DT], gi[DT];
    #pragma unroll
    for (int dd = 0; dd < DT; ++dd) { gr[dd] = 0.0f; gi[dd] = 0.0f; }

    #pragma unroll
    for (int kk = 0; kk < 16; ++kk) {
        float4 uf = *(const float4*)(uLc + kk * 4);
        float uu[4] = {uf.x, uf.y, uf.z, uf.w};
        #pragma unroll
        for (int c = 0; c < 4; ++c) {
            float uval = uu[c];
            #pragma unroll
            for (int dd = 0; dd < DT; ++dd) {
                float t  = fmaf(-li[dd], gi[dd], uval);
                float nr = fmaf(lr[dd], gr[dd], t);
                gi[dd] = fmaf(lr[dd], gi[dd], li[dd] * gr[dd]);
                gr[dd] = nr;
            }
        }
    }

    // ---- intra-wave Kogge-Stone scan over 16 chunks (stride-4 lanes) ----
    float pr[DT], pi[DT];             // lambda^64 -> squared to lambda^1024
    #pragma unroll
    for (int dd = 0; dd < DT; ++dd) {
        float e = __expf(av[dd] * dt64);
        float s, c; __sincosf(tv[dd] * dt64, &s, &c);
        pr[dd] = e * c; pi[dd] = e * s;
    }
    #pragma unroll
    for (int st = 1; st < 16; st <<= 1) {
        int src = lane - st * 4; if (src < 0) src = lane;
        #pragma unroll
        for (int dd = 0; dd < DT; ++dd) {
            float vr = __shfl(gr[dd], src, 64);
            float vi = __shfl(gi[dd], src, 64);
            vr = (m >= st) ? vr : 0.0f;
            vi = (m >= st) ? vi : 0.0f;
            gr[dd] = fmaf(pr[dd], vr, fmaf(-pi[dd], vi, gr[dd]));
            gi[dd] = fmaf(pr[dd], vi, fmaf( pi[dd], vr, gi[dd]));
        }
        #pragma unroll
        for (int dd = 0; dd < DT; ++dd) {   // p <- p^2
            float nr = fmaf(pr[dd], pr[dd], -(pi[dd] * pi[dd]));
            float ni = 2.0f * pr[dd] * pi[dd];
            pr[dd] = nr; pi[dd] = ni;
        }
    }

    // ---- inter-wave carry via 1KB LDS ----
    if (m == 15) {
        #pragma unroll
        for (int dd = 0; dd < DT; ++dd) {
            WT[wid][2 * (g * DT + dd)]     = gr[dd];
            WT[wid][2 * (g * DT + dd) + 1] = gi[dd];
        }
    }
    __syncthreads();
    float cr[DT], ci[DT];
    #pragma unroll
    for (int dd = 0; dd < DT; ++dd) { cr[dd] = 0.0f; ci[dd] = 0.0f; }
    for (int v = 0; v < wid; ++v) {         // wave-uniform trip count
        #pragma unroll
        for (int dd = 0; dd < DT; ++dd) {
            float tr = WT[v][2 * (g * DT + dd)];
            float ti = WT[v][2 * (g * DT + dd) + 1];
            float nr = fmaf(pr[dd], cr[dd], fmaf(-pi[dd], ci[dd], tr));
            float ni = fmaf(pr[dd], ci[dd], fmaf( pi[dd], cr[dd], ti));
            cr[dd] = nr; ci[dd] = ni;
        }
    }

    // ---- entry state: s = q*(excl + lambda^(64m)*carry) + w*lambda^(j*64-1) ----
    // lambda^(64m), w, lambda^(j*64-1) derived INLINE so av/tv/cr/ci die here.
    {
        int src4 = lane - 4; if (src4 < 0) src4 = lane;
        const float t1 = dt * (float)(j * LC - 1);
        const float tm = dt64 * (float)m;
        const int cbase = h * Dn + g * DT;
        #pragma unroll
        for (int dd = 0; dd < DT; ++dd) {
            float er = __shfl(gr[dd], src4, 64);   // exclusive intra-wave scan
            float ei = __shfl(gi[dd], src4, 64);
            er = (m >= 1) ? er : 0.0f;
            ei = (m >= 1) ? ei : 0.0f;
            float e3 = __expf(av[dd] * tm);
            float s3, c3; __sincosf(tv[dd] * tm, &s3, &c3);
            float amr = e3 * c3, ami = e3 * s3;
            float enr = er + fmaf(amr, cr[dd], -(ami * ci[dd]));
            float eni = ei + fmaf(amr, ci[dd],  (ami * cr[dd]));
            float w  = 2.0f * cin[cbase + dd] * x0in[cbase + dd];
            float e4 = __expf(av[dd] * t1);
            float s4, c4; __sincosf(tv[dd] * t1, &s4, &c4);
            gr[dd] = fmaf(q[dd], enr, w * e4 * c4);   // reuse gr/gi as s
            gi[dd] = fmaf(q[dd], eni, w * e4 * s4);
        }
    }

    // ---- pass B: s-scan (u from LDS), DPP 4-lane reduce, coalesced store ----
    const float Dk = Dsk[h];
    const float two_dt = 2.0f * dt;
    float4* o4g = (float4*)(out + (size_t)bh * Ln) + j * 16;

    #pragma unroll
    for (int kb = 0; kb < 4; ++kb) {
        float ovv[4];
        #pragma unroll
        for (int sg = 0; sg < 4; ++sg) {
            float4 uf = *(const float4*)(uLc + (kb * 4 + sg) * 4);
            float uu[4] = {uf.x, uf.y, uf.z, uf.w};
            #pragma unroll
            for (int c = 0; c < 4; ++c) {
                float uval = uu[c];
                float a0 = 0.0f, a1 = 0.0f;
                #pragma unroll
                for (int dd = 0; dd < DT; ++dd) {
                    float mq = q[dd] * uval;
                    float t  = fmaf(-li[dd], gi[dd], mq);
                    float nr = fmaf(lr[dd], gr[dd], t);
                    gi[dd] = fmaf(lr[dd], gi[dd], li[dd] * gr[dd]);
                    gr[dd] = nr;
                    if (dd & 1) a1 += nr; else a0 += nr;
                }
                float ps = a0 + a1;
                ps = dpp_add_x1(ps);
                ps = dpp_add_x2(ps);               // full 4-lane sum, VALU-only
                float y = fmaf(uval, Dk, two_dt * ps);
                if (sg == g) ovv[c] = y;
            }
        }
        float4 ov; ov.x = ovv[0]; ov.y = ovv[1]; ov.z = ovv[2]; ov.w = ovv[3];
        o4g[kb * 4 + g] = ov;
    }
}

extern "C" void kernel_launch(void* const* d_in, const int* in_sizes, int n_in,
                              void* d_out, int out_size, void* d_ws, size_t ws_size,
                              hipStream_t stream) {
    const float* u   = (const float*)d_in[0];
    const float* a   = (const float*)d_in[1];
    const float* th  = (const float*)d_in[2];
    const float* b   = (const float*)d_in[3];
    const float* c   = (const float*)d_in[4];
    const float* x0  = (const float*)d_in[5];
    const float* Dsk = (const float*)d_in[6];
    float* out = (float*)d_out;

    hipLaunchKernelGGL(hyena_scan, dim3(16 * Hn), dim3(TPB), 0, stream,
                       u, a, th, b, c, x0, Dsk, out);
}

// Round 11
// 215.192 us; speedup vs baseline: 3.1852x; 1.1629x over previous
//
#include <hip/hip_runtime.h>
#include <math.h>

// y[b,h,l] = (u *causal* f)[l] + u[b,h,l]*D_skip[h] + init[h,l]
// State-space scan: s = lambda*s + q*u;  y = 2dt*sum_d Re(s) + u*Dk
// lambda_d = exp((a_d + i*theta_d)*dt); init folded into s's initial state.
//
// block = 256 threads = one (b,h) row; thread = (chunk j = tid>>2 of 64 elems,
// d-group g = tid&3 of DT=8 states). u staged once in LDS; both passes read it
// via broadcast ds_read_b128. Kogge-Stone shuffle scan over chunks + LDS
// inter-wave carry. Quad-perm DPP adds for the 4-lane reduce.
//
// Two adjacent d-states packed per float2 -> v_pk_fma_f32 (VOP3P)
// halves VALU instruction issue in the two dominant scan loops.

#define Hn  256
#define Ln  4096
#define Dn  32
#define DT  8       // d-states per thread (4 packed pairs)
#define NP  4       // DT/2 packed pairs
#define LC  64      // elements per chunk
#define TPB 256
#define CS  68      // LDS chunk stride in floats
#define LDSPAD 4096 // floats; forces 4 blocks/CU (anti-spill occupancy cap)

typedef float v2 __attribute__((ext_vector_type(2)));

__device__ __forceinline__ v2 pfma(v2 a, v2 b, v2 c) {
    return __builtin_elementwise_fma(a, b, c);
}
__device__ __forceinline__ float dpp_add_x1(float v) {   // v += lane^1 (quad_perm)
    int t = __builtin_amdgcn_update_dpp(0, __float_as_int(v), 0xB1, 0xF, 0xF, true);
    return v + __int_as_float(t);
}
__device__ __forceinline__ float dpp_add_x2(float v) {   // v += lane^2 (quad_perm)
    int t = __builtin_amdgcn_update_dpp(0, __float_as_int(v), 0x4E, 0xF, 0xF, true);
    return v + __int_as_float(t);
}

__global__ __launch_bounds__(TPB)
__attribute__((amdgpu_waves_per_eu(4, 4)))
void hyena_scan(
    const float* __restrict__ u,      // (B,H,L)
    const float* __restrict__ ain,    // (1,H,D)
    const float* __restrict__ thin,   // (1,H,D)
    const float* __restrict__ bin,    // (1,H,D)
    const float* __restrict__ cin,    // (1,H,D)
    const float* __restrict__ x0in,   // (1,H,D)
    const float* __restrict__ Dsk,    // (1,H)
    float* __restrict__ out)          // (B,H,L)
{
    __shared__ float uL[64 * CS + LDSPAD];  // u staged + 16KB occupancy pad
    __shared__ float WTr[4][Dn];            // per-wave chunk-scan totals (re)
    __shared__ float WTi[4][Dn];            // per-wave chunk-scan totals (im)

    const int bh   = blockIdx.x;
    const int h    = bh & (Hn - 1);
    const int tid  = threadIdx.x;
    const int g    = tid & 3;         // d-group
    const int j    = tid >> 2;        // chunk 0..63
    const int m    = j & 15;          // chunk within wave
    const int wid  = tid >> 6;        // wave 0..3
    const int lane = tid & 63;
    const float dt   = 1.0f / (float)(Ln - 1);
    const float dt64 = dt * (float)LC;

    // ---- stage u into LDS (fully coalesced global reads) ----
    {
        const float4* ug = (const float4*)(u + (size_t)bh * Ln);
        #pragma unroll
        for (int r = 0; r < 4; ++r) {
            int i  = tid + r * TPB;          // float4 index 0..1023
            int cj = i >> 4, ct = i & 15;
            *(float4*)(uL + cj * CS + ct * 4) = ug[i];
        }
        if (tid == 0) uL[64 * CS + (bh & (LDSPAD - 1))] = 0.0f;  // keep pad live
    }

    // ---- coefficients: scalar av/tv + packed q, lambda ----
    float av[DT], tv[DT];
    v2 q2[NP], lr2[NP], li2[NP];
    {
        const int cbase = h * Dn + g * DT;
        #pragma unroll
        for (int p = 0; p < NP; ++p) {
            #pragma unroll
            for (int k = 0; k < 2; ++k) {
                const int dd = 2 * p + k;
                av[dd] = -fabsf(ain[cbase + dd]);
                tv[dd] = thin[cbase + dd];
                float qk = bin[cbase + dd] * cin[cbase + dd];
                float e1 = __expf(av[dd] * dt);
                float s1, c1; __sincosf(tv[dd] * dt, &s1, &c1);
                if (k == 0) { q2[p].x = qk; lr2[p].x = e1 * c1; li2[p].x = e1 * s1; }
                else        { q2[p].y = qk; lr2[p].y = e1 * c1; li2[p].y = e1 * s1; }
            }
        }
    }
    __syncthreads();

    const float* uLc = uL + j * CS;

    // ---- pass A: local G-scan from zero (packed pairs) ----
    v2 gr2[NP], gi2[NP];
    #pragma unroll
    for (int p = 0; p < NP; ++p) { gr2[p] = (v2){0.f, 0.f}; gi2[p] = (v2){0.f, 0.f}; }

    #pragma unroll
    for (int kk = 0; kk < 16; ++kk) {
        float4 uf = *(const float4*)(uLc + kk * 4);
        float uu[4] = {uf.x, uf.y, uf.z, uf.w};
        #pragma unroll
        for (int c = 0; c < 4; ++c) {
            v2 uu2 = (v2){uu[c], uu[c]};
            #pragma unroll
            for (int p = 0; p < NP; ++p) {
                v2 t  = pfma(-li2[p], gi2[p], uu2);
                v2 nr = pfma(lr2[p], gr2[p], t);
                gi2[p] = pfma(lr2[p], gi2[p], li2[p] * gr2[p]);
                gr2[p] = nr;
            }
        }
    }

    // ---- intra-wave Kogge-Stone scan over 16 chunks (packed) ----
    v2 pr2[NP], pi2[NP];              // lambda^64 -> squared to lambda^1024
    {
        #pragma unroll
        for (int p = 0; p < NP; ++p) {
            #pragma unroll
            for (int k = 0; k < 2; ++k) {
                const int dd = 2 * p + k;
                float e = __expf(av[dd] * dt64);
                float s, c; __sincosf(tv[dd] * dt64, &s, &c);
                if (k == 0) { pr2[p].x = e * c; pi2[p].x = e * s; }
                else        { pr2[p].y = e * c; pi2[p].y = e * s; }
            }
        }
    }
    const v2 zero2 = (v2){0.f, 0.f};
    #pragma unroll
    for (int st = 1; st < 16; st <<= 1) {
        int src = lane - st * 4; if (src < 0) src = lane;
        #pragma unroll
        for (int p = 0; p < NP; ++p) {
            v2 vr, vi;
            vr.x = __shfl(gr2[p].x, src, 64);
            vr.y = __shfl(gr2[p].y, src, 64);
            vi.x = __shfl(gi2[p].x, src, 64);
            vi.y = __shfl(gi2[p].y, src, 64);
            vr = (m >= st) ? vr : zero2;
            vi = (m >= st) ? vi : zero2;
            gr2[p] = pfma(pr2[p], vr, pfma(-pi2[p], vi, gr2[p]));
            gi2[p] = pfma(pr2[p], vi, pfma( pi2[p], vr, gi2[p]));
        }
        #pragma unroll
        for (int p = 0; p < NP; ++p) {        // p <- p^2
            v2 nr = pfma(pr2[p], pr2[p], -(pi2[p] * pi2[p]));
            v2 ni = (v2){2.f, 2.f} * (pr2[p] * pi2[p]);
            pr2[p] = nr; pi2[p] = ni;
        }
    }

    // ---- inter-wave carry via LDS (SoA so pairs load as b64) ----
    if (m == 15) {
        #pragma unroll
        for (int p = 0; p < NP; ++p) {
            const int i0 = g * DT + 2 * p;
            WTr[wid][i0]     = gr2[p].x;  WTr[wid][i0 + 1] = gr2[p].y;
            WTi[wid][i0]     = gi2[p].x;  WTi[wid][i0 + 1] = gi2[p].y;
        }
    }
    __syncthreads();
    v2 cr2[NP], ci2[NP];
    #pragma unroll
    for (int p = 0; p < NP; ++p) { cr2[p] = zero2; ci2[p] = zero2; }
    for (int v = 0; v < wid; ++v) {           // wave-uniform trip count
        #pragma unroll
        for (int p = 0; p < NP; ++p) {
            const int i0 = g * DT + 2 * p;
            v2 tr = *(const v2*)&WTr[v][i0];
            v2 ti = *(const v2*)&WTi[v][i0];
            v2 nr = pfma(pr2[p], cr2[p], pfma(-pi2[p], ci2[p], tr));
            v2 ni = pfma(pr2[p], ci2[p], pfma( pi2[p], cr2[p], ti));
            cr2[p] = nr; ci2[p] = ni;
        }
    }

    // ---- entry state: s = q*(excl + lambda^(64m)*carry) + w*lambda^(j*64-1) ----
    {
        int src4 = lane - 4; if (src4 < 0) src4 = lane;
        const float t1 = dt * (float)(j * LC - 1);
        const float tm = dt64 * (float)m;
        const int cbase = h * Dn + g * DT;
        #pragma unroll
        for (int p = 0; p < NP; ++p) {
            float s0r[2], s0i[2];
            #pragma unroll
            for (int k = 0; k < 2; ++k) {
                const int dd = 2 * p + k;
                float grk = (k == 0) ? gr2[p].x : gr2[p].y;
                float gik = (k == 0) ? gi2[p].x : gi2[p].y;
                float crk = (k == 0) ? cr2[p].x : cr2[p].y;
                float cik = (k == 0) ? ci2[p].x : ci2[p].y;
                float qk  = (k == 0) ? q2[p].x  : q2[p].y;
                float er = __shfl(grk, src4, 64);     // exclusive intra-wave scan
                float ei = __shfl(gik, src4, 64);
                er = (m >= 1) ? er : 0.0f;
                ei = (m >= 1) ? ei : 0.0f;
                float e3 = __expf(av[dd] * tm);
                float s3, c3; __sincosf(tv[dd] * tm, &s3, &c3);
                float amr = e3 * c3, ami = e3 * s3;
                float enr = er + fmaf(amr, crk, -(ami * cik));
                float eni = ei + fmaf(amr, cik,  (ami * crk));
                float w  = 2.0f * cin[cbase + dd] * x0in[cbase + dd];
                float e4 = __expf(av[dd] * t1);
                float s4, c4; __sincosf(tv[dd] * t1, &s4, &c4);
                s0r[k] = fmaf(qk, enr, w * e4 * c4);
                s0i[k] = fmaf(qk, eni, w * e4 * s4);
            }
            gr2[p] = (v2){s0r[0], s0r[1]};            // reuse gr2/gi2 as s
            gi2[p] = (v2){s0i[0], s0i[1]};
        }
    }

    // ---- pass B: packed s-scan (u from LDS), DPP 4-lane reduce, store ----
    const float Dk = Dsk[h];
    const float two_dt = 2.0f * dt;
    float4* o4g = (float4*)(out + (size_t)bh * Ln) + j * 16;

    #pragma unroll
    for (int kb = 0; kb < 4; ++kb) {
        float ovv[4];
        #pragma unroll
        for (int sg = 0; sg < 4; ++sg) {
            float4 uf = *(const float4*)(uLc + (kb * 4 + sg) * 4);
            float uu[4] = {uf.x, uf.y, uf.z, uf.w};
            #pragma unroll
            for (int c = 0; c < 4; ++c) {
                float uval = uu[c];
                v2 uu2 = (v2){uval, uval};
                v2 acc = zero2;
                #pragma unroll
                for (int p = 0; p < NP; ++p) {
                    v2 mq = q2[p] * uu2;
                    v2 t  = pfma(-li2[p], gi2[p], mq);
                    v2 nr = pfma(lr2[p], gr2[p], t);
                    gi2[p] = pfma(lr2[p], gi2[p], li2[p] * gr2[p]);
                    gr2[p] = nr;
                    acc = acc + nr;
                }
                float ps = acc.x + acc.y;
                ps = dpp_add_x1(ps);
                ps = dpp_add_x2(ps);               // full 4-lane sum
                float y = fmaf(uval, Dk, two_dt * ps);
                if (sg == g) ovv[c] = y;
            }
        }
        float4 ov; ov.x = ovv[0]; ov.y = ovv[1]; ov.z = ovv[2]; ov.w = ovv[3];
        o4g[kb * 4 + g] = ov;
    }
}

extern "C" void kernel_launch(void* const* d_in, const int* in_sizes, int n_in,
                              void* d_out, int out_size, void* d_ws, size_t ws_size,
                              hipStream_t stream) {
    const float* u   = (const float*)d_in[0];
    const float* a   = (const float*)d_in[1];
    const float* th  = (const float*)d_in[2];
    const float* b   = (const float*)d_in[3];
    const float* c   = (const float*)d_in[4];
    const float* x0  = (const float*)d_in[5];
    const float* Dsk = (const float*)d_in[6];
    float* out = (float*)d_out;

    hipLaunchKernelGGL(hyena_scan, dim3(16 * Hn), dim3(TPB), 0, stream,
                       u, a, th, b, c, x0, Dsk, out);
}